// Round 1
// baseline (251.799 us; speedup 1.0000x reference)
//
#include <hip/hip_runtime.h>

// Ranking-loss scalar reduction:
//   loss = 0.2 * (pos*sum_neg - neg*sum_pos) / (pos*neg)
// Needs sum(y), sum(y*lab), sum(lab) over N=32M floats/ints (256 MB read).
//
// R1: same-address fp64 atomics serialize -> per-block partials + stage2.
// R2/R3: three loop structures all pin at ~105us = 2.5 TB/s consumed with
// VALUBusy ~6%, occupancy ~65%, HBM at 1.25 TB/s -> limiter is the L2
// allocate/fill path for a zero-reuse stream (MLP arithmetic rules out
// latency: even 1 outstanding 1KiB load/wave at full occupancy = 32KiB/CU
// in flight vs ~9KiB needed for 6.3 TB/s at 900cy).
// R4: __builtin_nontemporal_load (nt bit) -> reduce dropped below the 77us
// fill dispatches (absent from rocprof top-5) but nt still ALLOCATES in L2
// (LRU hint only).
// R5 (this): system-scope read-through loads (sc0 sc1 nt) via inline asm --
// L2 is not the system coherence point, so sc0+sc1 loads skip L2 allocation
// entirely and are served by the MALL/HBM side, which the harness fill
// kernels prove sustains ~7 TB/s for zero-reuse streams.
//   - waitcnt vmcnt(0) is INSIDE the asm block (no rule-18 hazard).
//   - "=&v" earlyclobber: async load returns must not overwrite address
//     VGPRs of later not-yet-issued loads in the same block.
//   - y and lab share the same 32-bit byte offsets (both 16B/elem), two
//     SGPR bases -> ~50 live VGPRs, fits the 64-VGPR cap of (256,8).
//
// fp64 accumulation of per-iteration fp32 partials: final expression is a
// catastrophic cancellation; fp32-partial error contributes ~1e-11 to the
// loss vs the 6e-7 harness threshold.

#define NBLK 2048
#define TPB 256
#define UNROLL 4

typedef float  f4 __attribute__((ext_vector_type(4)));
typedef int    i4 __attribute__((ext_vector_type(4)));

__global__ __launch_bounds__(TPB, 8)
void aux_loss_reduce(const float* __restrict__ y,
                     const int* __restrict__ lab,
                     double* __restrict__ part, int n) {
    const int n4 = n >> 2;
    const f4* __restrict__ y4 = (const f4*)y;
    const i4* __restrict__ l4 = (const i4*)lab;

    // contiguous chunk per block
    const int chunk = (n4 + NBLK - 1) / NBLK;          // 4096 for N=32M
    const int base = blockIdx.x * chunk;
    const int end = min(base + chunk, n4);
    const int span = TPB * UNROLL;
    const int nfull = (end - base) / span;             // full, bounds-check-free iters

    double s_all = 0.0, s_pos = 0.0;
    long long cnt = 0;

    // byte offset into both streams (16 B per f4/i4 element), shared by y and lab
    unsigned o0 = (unsigned)(base + (int)threadIdx.x) * 16u;
    const unsigned step = (unsigned)span * 16u;        // 16 KB per iteration

    int i0 = base;
    for (int it = 0; it < nfull; ++it, i0 += span) {
        f4 v0, v1, v2, v3;
        i4 l0, l1, l2, l3;
        const unsigned o1 = o0 + (unsigned)(1 * TPB * 16);
        const unsigned o2 = o0 + (unsigned)(2 * TPB * 16);
        const unsigned o3 = o0 + (unsigned)(3 * TPB * 16);
        // 8 system-scope (L2 read-through) nontemporal 16B loads in flight,
        // then drain. At 8 waves/SIMD this is 128KiB/CU outstanding -- far
        // above the ~9KiB needed to cover HBM latency at full BW.
        asm volatile(
            "global_load_dwordx4 %0, %8, %12 sc0 sc1 nt\n\t"
            "global_load_dwordx4 %1, %9, %12 sc0 sc1 nt\n\t"
            "global_load_dwordx4 %2, %10, %12 sc0 sc1 nt\n\t"
            "global_load_dwordx4 %3, %11, %12 sc0 sc1 nt\n\t"
            "global_load_dwordx4 %4, %8, %13 sc0 sc1 nt\n\t"
            "global_load_dwordx4 %5, %9, %13 sc0 sc1 nt\n\t"
            "global_load_dwordx4 %6, %10, %13 sc0 sc1 nt\n\t"
            "global_load_dwordx4 %7, %11, %13 sc0 sc1 nt\n\t"
            "s_waitcnt vmcnt(0)"
            : "=&v"(v0), "=&v"(v1), "=&v"(v2), "=&v"(v3),
              "=&v"(l0), "=&v"(l1), "=&v"(l2), "=&v"(l3)
            : "v"(o0), "v"(o1), "v"(o2), "v"(o3),
              "s"(y), "s"(lab)
            : "memory");

        float pa = 0.f, pp = 0.f;
        int pc = 0;
#define ACC(v, l)                                                         \
        do {                                                              \
            pa += ((v).x + (v).y) + ((v).z + (v).w);                      \
            pp += ((l).x ? (v).x : 0.f) + ((l).y ? (v).y : 0.f)           \
                + ((l).z ? (v).z : 0.f) + ((l).w ? (v).w : 0.f);          \
            pc += (l).x + (l).y + (l).z + (l).w;                          \
        } while (0)
        ACC(v0, l0);
        ACC(v1, l1);
        ACC(v2, l2);
        ACC(v3, l3);
#undef ACC
        s_all += (double)pa;
        s_pos += (double)pp;
        cnt += pc;
        o0 += step;
    }
    // remainder iteration (bounds-checked) — no-op when chunk % span == 0
    for (int i = i0 + (int)threadIdx.x; i < end; i += TPB) {
        f4 v = __builtin_nontemporal_load(&y4[i]);
        i4 l = __builtin_nontemporal_load(&l4[i]);
        float pa = (v.x + v.y) + (v.z + v.w);
        float pp = (l.x ? v.x : 0.f) + (l.y ? v.y : 0.f)
                 + (l.z ? v.z : 0.f) + (l.w ? v.w : 0.f);
        s_all += (double)pa;
        s_pos += (double)pp;
        cnt += l.x + l.y + l.z + l.w;
    }

    // scalar tail (n % 4 elements) — block 0 only
    if (blockIdx.x == 0) {
        for (int j = (n4 << 2) + (int)threadIdx.x; j < n; j += TPB) {
            const float v = y[j];
            const int l = lab[j];
            s_all += (double)v;
            if (l) { s_pos += (double)v; cnt += l; }
        }
    }

    double c = (double)cnt;

    // wave-level reduce (64 lanes)
    for (int off = 32; off > 0; off >>= 1) {
        s_all += __shfl_down(s_all, off);
        s_pos += __shfl_down(s_pos, off);
        c     += __shfl_down(c, off);
    }

    // cross-wave via LDS (256-thread block = 4 waves)
    __shared__ double sh_all[4], sh_pos[4], sh_cnt[4];
    const int wave = threadIdx.x >> 6;
    const int lane = threadIdx.x & 63;
    if (lane == 0) { sh_all[wave] = s_all; sh_pos[wave] = s_pos; sh_cnt[wave] = c; }
    __syncthreads();

    if (threadIdx.x == 0) {
        double a = 0.0, p = 0.0, cc = 0.0;
        for (int w = 0; w < 4; ++w) { a += sh_all[w]; p += sh_pos[w]; cc += sh_cnt[w]; }
        // SoA partials: contention-free plain stores, coalesced stage-2 reads
        part[blockIdx.x]            = a;
        part[NBLK + blockIdx.x]     = p;
        part[2 * NBLK + blockIdx.x] = cc;
    }
}

__global__ void aux_loss_stage2(const double* __restrict__ part,
                                float* __restrict__ out, double n_total) {
    double a = 0.0, p = 0.0, cc = 0.0;
    for (int i = threadIdx.x; i < NBLK; i += blockDim.x) {
        a  += part[i];
        p  += part[NBLK + i];
        cc += part[2 * NBLK + i];
    }
    for (int off = 32; off > 0; off >>= 1) {
        a  += __shfl_down(a, off);
        p  += __shfl_down(p, off);
        cc += __shfl_down(cc, off);
    }
    __shared__ double sh_a[4], sh_p[4], sh_c[4];
    const int wave = threadIdx.x >> 6;
    const int lane = threadIdx.x & 63;
    if (lane == 0) { sh_a[wave] = a; sh_p[wave] = p; sh_c[wave] = cc; }
    __syncthreads();

    if (threadIdx.x == 0) {
        double sum_all = 0.0, sum_pos = 0.0, pos = 0.0;
        for (int w = 0; w < 4; ++w) { sum_all += sh_a[w]; sum_pos += sh_p[w]; pos += sh_c[w]; }
        const double neg = n_total - pos;
        const double sum_neg = sum_all - sum_pos;
        double loss = 0.0;
        if (pos > 0.0 && neg > 0.0) {
            loss = 0.2 * (pos * sum_neg - neg * sum_pos) / (pos * neg);
        }
        out[0] = (float)loss;
    }
}

extern "C" void kernel_launch(void* const* d_in, const int* in_sizes, int n_in,
                              void* d_out, int out_size, void* d_ws, size_t ws_size,
                              hipStream_t stream) {
    const float* y = (const float*)d_in[0];
    const int* lab = (const int*)d_in[1];
    int n = in_sizes[0];

    double* part = (double*)d_ws;  // 3 * NBLK doubles = 48 KB of scratch
    // No memset needed: every slot is unconditionally written by stage 1.

    aux_loss_reduce<<<NBLK, TPB, 0, stream>>>(y, lab, part, n);
    aux_loss_stage2<<<1, TPB, 0, stream>>>(part, (float*)d_out, (double)n);
}